// Round 1
// baseline (547.057 us; speedup 1.0000x reference)
//
#include <hip/hip_runtime.h>
#include <stdint.h>

// Problem constants (from reference)
constexpr int BB = 64, TT = 200;
constexpr int M  = BB * TT;          // 12800 rows
constexpr int DSEM = 768, DPR = 384;
constexpr int Kd = DSEM + DPR;       // 1152
constexpr int Nd = 2048;             // d_model
constexpr int NUM_ITEMS = 100000;

typedef short bf16x8 __attribute__((ext_vector_type(8)));  // 8 bf16 (4 VGPRs)
typedef float f32x4  __attribute__((ext_vector_type(4)));

__device__ __forceinline__ unsigned short f2bf(float f) {
  union { float f; uint32_t u; } v; v.f = f;
  uint32_t u = v.u;
  u += 0x7fffu + ((u >> 16) & 1u);   // RNE
  return (unsigned short)(u >> 16);
}

// ---- prep 1: proj_w fp32 -> bf16 (2048*1152 = 2,359,296 elems, /4 = 589,824 thr = 2304*256 exact)
__global__ void wconv_kernel(const float* __restrict__ w, unsigned short* __restrict__ wb) {
  int g = blockIdx.x * blockDim.x + threadIdx.x;
  int e = g * 4;
  float4 v = *(const float4*)(w + e);
  ushort4 o;
  o.x = f2bf(v.x); o.y = f2bf(v.y); o.z = f2bf(v.z); o.w = f2bf(v.w);
  *(ushort4*)(wb + e) = o;
}

// ---- prep 2: gather + concat + convert + zero-invalid-rows into A[M][Kd] bf16
// 12800*1152/4 = 3,686,400 groups = 14400*256 exact. 288 groups of 4 per row.
__global__ void gather_kernel(const int* __restrict__ ids,
                              const float* __restrict__ Esem,
                              const float* __restrict__ vpr,
                              unsigned short* __restrict__ A) {
  unsigned g = blockIdx.x * blockDim.x + threadIdx.x;
  unsigned row = g / 288u;
  unsigned col = (g - row * 288u) * 4u;
  int id = ids[row];
  bool valid = (id >= 0) && (id < NUM_ITEMS);
  int safe = valid ? id : 0;
  const float* src = (col < (unsigned)DSEM)
                       ? (Esem + (size_t)safe * DSEM + col)
                       : (vpr  + (size_t)safe * DPR  + (col - DSEM));
  float4 v = *(const float4*)src;
  if (!valid) { v.x = 0.f; v.y = 0.f; v.z = 0.f; v.w = 0.f; }
  ushort4 o;
  o.x = f2bf(v.x); o.y = f2bf(v.y); o.z = f2bf(v.z); o.w = f2bf(v.w);
  *(ushort4*)(A + (size_t)row * Kd + col) = o;
}

// ---- prep 3: amask + tok_item_ids as floats
__global__ void mask_kernel(const int* __restrict__ ids,
                            float* __restrict__ amask, float* __restrict__ tok) {
  int i = blockIdx.x * blockDim.x + threadIdx.x;
  if (i >= M) return;
  int id = ids[i];
  bool valid = (id >= 0) && (id < NUM_ITEMS);
  amask[i] = valid ? 1.0f : 0.0f;
  tok[i]   = valid ? (float)id : -1.0f;
}

// ---- async 16B global->LDS (wave-uniform LDS base + lane*16 semantics)
__device__ __forceinline__ void async16(const void* gsrc, void* ldst) {
  __builtin_amdgcn_global_load_lds(
      (const __attribute__((address_space(1))) unsigned int*)gsrc,
      (__attribute__((address_space(3))) unsigned int*)ldst,
      16, 0, 0);
}

// ---- m97-structure GEMM: C[M,Nd] = A[M,Kd](bf16) @ W[Nd,Kd]^T(bf16), fp32 out
// 128x128 tile, BK=32, 4 waves in 2x2, each wave 64x64 via 4x4 MFMA 16x16x32.
__global__ __launch_bounds__(256) void gemm_kernel(const unsigned short* __restrict__ A,
                                                   const unsigned short* __restrict__ Wb,
                                                   float* __restrict__ C) {
  __shared__ unsigned short lds_a[128 * 32];  // 8 KB, row-major [row][32] — NO padding (global_load_lds)
  __shared__ unsigned short lds_b[128 * 32];

  const int tid  = threadIdx.x;
  const int lane = tid & 63;
  const int wave = tid >> 6;
  const int wm = wave >> 1, wn = wave & 1;
  const int quad = lane >> 4, lm = lane & 15;
  const int m0 = blockIdx.x * 128;
  const int n0 = blockIdx.y * 128;

  // staging map: idx = r*256 + tid -> LDS bytes [idx*16, idx*16+16); row = idx>>2, col = (idx&3)*8
  const int srow = tid >> 2;        // 0..63 (plus r*64)
  const int scol = (tid & 3) * 8;   // element offset in K

  f32x4 acc[4][4];
#pragma unroll
  for (int i = 0; i < 4; ++i)
#pragma unroll
    for (int j = 0; j < 4; ++j) acc[i][j] = (f32x4){0.f, 0.f, 0.f, 0.f};

  for (int kt = 0; kt < Kd / 32; ++kt) {
    const int k0 = kt * 32;
#pragma unroll
    for (int r = 0; r < 2; ++r) {
      const unsigned short* ga = A + (size_t)(m0 + r * 64 + srow) * Kd + k0 + scol;
      async16(ga, lds_a + (size_t)(r * 256 + wave * 64) * 8);   // wave-uniform base
      const unsigned short* gb = Wb + (size_t)(n0 + r * 64 + srow) * Kd + k0 + scol;
      async16(gb, lds_b + (size_t)(r * 256 + wave * 64) * 8);
    }
    __syncthreads();

    bf16x8 af[4], bf[4];
#pragma unroll
    for (int mi = 0; mi < 4; ++mi)
      af[mi] = *(const bf16x8*)(lds_a + (wm * 64 + mi * 16 + lm) * 32 + quad * 8);
#pragma unroll
    for (int ni = 0; ni < 4; ++ni)
      bf[ni] = *(const bf16x8*)(lds_b + (wn * 64 + ni * 16 + lm) * 32 + quad * 8);
#pragma unroll
    for (int mi = 0; mi < 4; ++mi)
#pragma unroll
      for (int ni = 0; ni < 4; ++ni)
        acc[mi][ni] = __builtin_amdgcn_mfma_f32_16x16x32_bf16(af[mi], bf[ni], acc[mi][ni], 0, 0, 0);
    __syncthreads();
  }

  // epilogue: C/D layout col = lane&15, row = quad*4 + reg  [measured m89/m91]
#pragma unroll
  for (int mi = 0; mi < 4; ++mi) {
#pragma unroll
    for (int ni = 0; ni < 4; ++ni) {
      const int row = m0 + wm * 64 + mi * 16 + quad * 4;
      const int col = n0 + wn * 64 + ni * 16 + lm;
#pragma unroll
      for (int i = 0; i < 4; ++i)
        C[(size_t)(row + i) * Nd + col] = acc[mi][ni][i];
    }
  }
}

extern "C" void kernel_launch(void* const* d_in, const int* in_sizes, int n_in,
                              void* d_out, int out_size, void* d_ws, size_t ws_size,
                              hipStream_t stream) {
  const int*   ids  = (const int*)d_in[0];
  // d_in[1] = lengths: unused (padding already encoded as -1 in ids)
  const float* Esem = (const float*)d_in[2];
  const float* vpr  = (const float*)d_in[3];
  const float* pw   = (const float*)d_in[4];

  float* out_emb   = (float*)d_out;                 // [M, Nd]
  float* out_amask = out_emb + (size_t)M * Nd;      // [M]
  float* out_tok   = out_amask + M;                 // [M]

  unsigned short* A  = (unsigned short*)d_ws;        // [M, Kd] bf16 = 29,491,200 B
  unsigned short* Wb = A + (size_t)M * Kd;           // [Nd, Kd] bf16 = 4,718,592 B (offset 256-aligned)

  gather_kernel<<<(M * Kd / 4) / 256, 256, 0, stream>>>(ids, Esem, vpr, A);
  wconv_kernel<<<(Nd * Kd / 4) / 256, 256, 0, stream>>>(pw, Wb);
  mask_kernel<<<(M + 255) / 256, 256, 0, stream>>>(ids, out_amask, out_tok);
  gemm_kernel<<<dim3(M / 128, Nd / 128), 256, 0, stream>>>(A, Wb, out_emb);
}

// Round 2
// 526.326 us; speedup vs baseline: 1.0394x; 1.0394x over previous
//
#include <hip/hip_runtime.h>
#include <stdint.h>

// Problem constants (from reference)
constexpr int BB = 64, TT = 200;
constexpr int M  = BB * TT;          // 12800 rows
constexpr int DSEM = 768, DPR = 384;
constexpr int Kd = DSEM + DPR;       // 1152
constexpr int Nd = 2048;             // d_model
constexpr int NUM_ITEMS = 100000;
constexpr int BK = 64;               // K-tile (halves barrier count vs 32)

constexpr int GATHER_BLOCKS = (M * Kd / 4) / 256;   // 14400
constexpr int WCONV_BLOCKS  = (Nd * Kd / 4) / 256;  // 2304
constexpr int MASK_BLOCKS   = (M + 255) / 256;      // 50

typedef short bf16x8 __attribute__((ext_vector_type(8)));  // 8 bf16 (4 VGPRs)
typedef float f32x4  __attribute__((ext_vector_type(4)));

__device__ __forceinline__ unsigned short f2bf(float f) {
  union { float f; uint32_t u; } v; v.f = f;
  uint32_t u = v.u;
  u += 0x7fffu + ((u >> 16) & 1u);   // RNE
  return (unsigned short)(u >> 16);
}

// ---- fused prep: gather+convert A | proj_w->bf16 | amask/tok  (one dispatch)
__global__ void prep_kernel(const int* __restrict__ ids,
                            const float* __restrict__ Esem,
                            const float* __restrict__ vpr,
                            const float* __restrict__ pw,
                            unsigned short* __restrict__ A,
                            unsigned short* __restrict__ Wb,
                            float* __restrict__ amask,
                            float* __restrict__ tok) {
  const int b = blockIdx.x;
  const int tid = threadIdx.x;
  if (b < GATHER_BLOCKS) {
    // gather + concat + bf16-convert + zero invalid rows into A[M][Kd]
    unsigned g = (unsigned)b * 256u + tid;
    unsigned row = g / 288u;                 // 288 float4-groups per row
    unsigned col = (g - row * 288u) * 4u;
    int id = ids[row];
    bool valid = (id >= 0) && (id < NUM_ITEMS);
    int safe = valid ? id : 0;
    const float* src = (col < (unsigned)DSEM)
                         ? (Esem + (size_t)safe * DSEM + col)
                         : (vpr  + (size_t)safe * DPR  + (col - DSEM));
    float4 v = *(const float4*)src;
    if (!valid) { v.x = 0.f; v.y = 0.f; v.z = 0.f; v.w = 0.f; }
    ushort4 o;
    o.x = f2bf(v.x); o.y = f2bf(v.y); o.z = f2bf(v.z); o.w = f2bf(v.w);
    *(ushort4*)(A + (size_t)row * Kd + col) = o;
  } else if (b < GATHER_BLOCKS + WCONV_BLOCKS) {
    int g = (b - GATHER_BLOCKS) * 256 + tid;
    int e = g * 4;
    float4 v = *(const float4*)(pw + e);
    ushort4 o;
    o.x = f2bf(v.x); o.y = f2bf(v.y); o.z = f2bf(v.z); o.w = f2bf(v.w);
    *(ushort4*)(Wb + e) = o;
  } else {
    int i = (b - GATHER_BLOCKS - WCONV_BLOCKS) * 256 + tid;
    if (i < M) {
      int id = ids[i];
      bool valid = (id >= 0) && (id < NUM_ITEMS);
      amask[i] = valid ? 1.0f : 0.0f;
      tok[i]   = valid ? (float)id : -1.0f;
    }
  }
}

// ---- async 16B global->LDS (wave-uniform LDS base + lane*16 semantics)
__device__ __forceinline__ void async16(const void* gsrc, void* ldst) {
  __builtin_amdgcn_global_load_lds(
      (const __attribute__((address_space(1))) unsigned int*)gsrc,
      (__attribute__((address_space(3))) unsigned int*)ldst,
      16, 0, 0);
}

// ---- GEMM: C[M,Nd] = A[M,Kd](bf16) @ W[Nd,Kd]^T(bf16), fp32 out
// 128x128 tile, BK=64 (18 K-iters), 4 waves 2x2, wave = 64x64 via 4x4 MFMA 16x16x32.
// LDS layout: [row][BK] with XOR chunk swizzle: LDS chunk c of row r holds
// global chunk (c ^ (r&7)) — makes fragment ds_read_b128 2-way (free) instead
// of 16-way bank-aliased at 128B row stride.
__global__ __launch_bounds__(256) void gemm_kernel(const unsigned short* __restrict__ A,
                                                   const unsigned short* __restrict__ Wb,
                                                   float* __restrict__ C) {
  __shared__ unsigned short lds_a[128 * BK];  // 16 KB
  __shared__ unsigned short lds_b[128 * BK];  // 16 KB

  const int tid  = threadIdx.x;
  const int lane = tid & 63;
  const int wave = tid >> 6;
  const int wm = wave >> 1, wn = wave & 1;
  const int quad = lane >> 4, lm = lane & 15;
  const int m0 = blockIdx.x * 128;
  const int n0 = blockIdx.y * 128;

  // staging: slot idx = r*256 + tid -> LDS row = idx>>3, chunk = idx&7 (8 elems)
  const int srow   = tid >> 3;   // + r*32
  const int schunk = tid & 7;

  f32x4 acc[4][4];
#pragma unroll
  for (int i = 0; i < 4; ++i)
#pragma unroll
    for (int j = 0; j < 4; ++j) acc[i][j] = (f32x4){0.f, 0.f, 0.f, 0.f};

  for (int kt = 0; kt < Kd / BK; ++kt) {
    const int k0 = kt * BK;
#pragma unroll
    for (int r = 0; r < 4; ++r) {
      const int row = r * 32 + srow;
      const int gch = schunk ^ (row & 7);      // XOR swizzle (global side is per-lane)
      const unsigned short* ga = A + (size_t)(m0 + row) * Kd + k0 + gch * 8;
      async16(ga, lds_a + (size_t)(r * 256 + wave * 64) * 8);  // wave-uniform base
      const unsigned short* gb = Wb + (size_t)(n0 + row) * Kd + k0 + gch * 8;
      async16(gb, lds_b + (size_t)(r * 256 + wave * 64) * 8);
    }
    __syncthreads();

#pragma unroll
    for (int h = 0; h < 2; ++h) {              // two 32-wide k-slabs per BK=64
      bf16x8 af[4], bfr[4];
#pragma unroll
      for (int mi = 0; mi < 4; ++mi) {
        const int row = wm * 64 + mi * 16 + lm;
        af[mi] = *(const bf16x8*)(lds_a + row * BK + ((h * 4 + quad) ^ (row & 7)) * 8);
      }
#pragma unroll
      for (int ni = 0; ni < 4; ++ni) {
        const int row = wn * 64 + ni * 16 + lm;
        bfr[ni] = *(const bf16x8*)(lds_b + row * BK + ((h * 4 + quad) ^ (row & 7)) * 8);
      }
#pragma unroll
      for (int mi = 0; mi < 4; ++mi)
#pragma unroll
        for (int ni = 0; ni < 4; ++ni)
          acc[mi][ni] = __builtin_amdgcn_mfma_f32_16x16x32_bf16(af[mi], bfr[ni], acc[mi][ni], 0, 0, 0);
    }
    __syncthreads();
  }

  // epilogue: C/D layout col = lane&15, row = quad*4 + reg  [measured m89/m91]
#pragma unroll
  for (int mi = 0; mi < 4; ++mi) {
#pragma unroll
    for (int ni = 0; ni < 4; ++ni) {
      const int row = m0 + wm * 64 + mi * 16 + quad * 4;
      const int col = n0 + wn * 64 + ni * 16 + lm;
#pragma unroll
      for (int i = 0; i < 4; ++i)
        C[(size_t)(row + i) * Nd + col] = acc[mi][ni][i];
    }
  }
}

extern "C" void kernel_launch(void* const* d_in, const int* in_sizes, int n_in,
                              void* d_out, int out_size, void* d_ws, size_t ws_size,
                              hipStream_t stream) {
  const int*   ids  = (const int*)d_in[0];
  // d_in[1] = lengths: unused (padding already encoded as -1 in ids)
  const float* Esem = (const float*)d_in[2];
  const float* vpr  = (const float*)d_in[3];
  const float* pw   = (const float*)d_in[4];

  float* out_emb   = (float*)d_out;                 // [M, Nd]
  float* out_amask = out_emb + (size_t)M * Nd;      // [M]
  float* out_tok   = out_amask + M;                 // [M]

  unsigned short* A  = (unsigned short*)d_ws;        // [M, Kd] bf16
  unsigned short* Wb = A + (size_t)M * Kd;           // [Nd, Kd] bf16

  prep_kernel<<<GATHER_BLOCKS + WCONV_BLOCKS + MASK_BLOCKS, 256, 0, stream>>>(
      ids, Esem, vpr, pw, A, Wb, out_amask, out_tok);
  gemm_kernel<<<dim3(M / 128, Nd / 128), 256, 0, stream>>>(A, Wb, out_emb);
}

// Round 3
// 523.505 us; speedup vs baseline: 1.0450x; 1.0054x over previous
//
#include <hip/hip_runtime.h>
#include <stdint.h>

// Problem constants (from reference)
constexpr int BB = 64, TT = 200;
constexpr int M  = BB * TT;          // 12800 rows
constexpr int DSEM = 768, DPR = 384;
constexpr int Kd = DSEM + DPR;       // 1152
constexpr int Nd = 2048;             // d_model
constexpr int NUM_ITEMS = 100000;
constexpr int BK = 64;               // K-tile

constexpr int GATHER_BLOCKS = (M * Kd / 8) / 256;   // 7200  (8 elems/thread)
constexpr int WCONV_BLOCKS  = (Nd * Kd / 8) / 256;  // 1152
constexpr int MASK_BLOCKS   = (M + 255) / 256;      // 50

typedef short bf16x8 __attribute__((ext_vector_type(8)));  // 8 bf16 (4 VGPRs)
typedef float f32x4  __attribute__((ext_vector_type(4)));

__device__ __forceinline__ unsigned short f2bf(float f) {
  union { float f; uint32_t u; } v; v.f = f;
  uint32_t u = v.u;
  u += 0x7fffu + ((u >> 16) & 1u);   // RNE
  return (unsigned short)(u >> 16);
}

__device__ __forceinline__ ushort4 cvt8(float4 a, float4 b2) {
  // pack two float4 -> 8 bf16 in a 16B ushort... (returned as two ushort4 stores merged by caller)
  ushort4 dummy; return dummy; // unused placeholder (kept out of real path)
}

// ---- fused prep: gather+convert A | proj_w->bf16 | amask/tok  (one dispatch)
__global__ void prep_kernel(const int* __restrict__ ids,
                            const float* __restrict__ Esem,
                            const float* __restrict__ vpr,
                            const float* __restrict__ pw,
                            unsigned short* __restrict__ A,
                            unsigned short* __restrict__ Wb,
                            float* __restrict__ amask,
                            float* __restrict__ tok) {
  const int b = blockIdx.x;
  const int tid = threadIdx.x;
  if (b < GATHER_BLOCKS) {
    // gather + concat + bf16-convert + zero invalid rows into A[M][Kd]
    // 8 elems/thread: 144 chunks per row; chunk boundary 96 splits sem|prompt exactly.
    unsigned g = (unsigned)b * 256u + tid;
    unsigned row = g / 144u;
    unsigned col = (g - row * 144u) * 8u;
    int id = ids[row];
    bool valid = (id >= 0) && (id < NUM_ITEMS);
    int safe = valid ? id : 0;
    const float* src = (col < (unsigned)DSEM)
                         ? (Esem + (size_t)safe * DSEM + col)
                         : (vpr  + (size_t)safe * DPR  + (col - DSEM));
    float4 v0 = *(const float4*)src;
    float4 v1 = *(const float4*)(src + 4);
    if (!valid) {
      v0.x = v0.y = v0.z = v0.w = 0.f;
      v1.x = v1.y = v1.z = v1.w = 0.f;
    }
    ushort4 o0, o1;
    o0.x = f2bf(v0.x); o0.y = f2bf(v0.y); o0.z = f2bf(v0.z); o0.w = f2bf(v0.w);
    o1.x = f2bf(v1.x); o1.y = f2bf(v1.y); o1.z = f2bf(v1.z); o1.w = f2bf(v1.w);
    unsigned short* dst = A + (size_t)row * Kd + col;
    *(ushort4*)dst       = o0;   // compiler merges into one 16B store (aligned: col%8==0)
    *(ushort4*)(dst + 4) = o1;
  } else if (b < GATHER_BLOCKS + WCONV_BLOCKS) {
    int g = (b - GATHER_BLOCKS) * 256 + tid;
    int e = g * 8;
    float4 v0 = *(const float4*)(pw + e);
    float4 v1 = *(const float4*)(pw + e + 4);
    ushort4 o0, o1;
    o0.x = f2bf(v0.x); o0.y = f2bf(v0.y); o0.z = f2bf(v0.z); o0.w = f2bf(v0.w);
    o1.x = f2bf(v1.x); o1.y = f2bf(v1.y); o1.z = f2bf(v1.z); o1.w = f2bf(v1.w);
    *(ushort4*)(Wb + e)     = o0;
    *(ushort4*)(Wb + e + 4) = o1;
  } else {
    int i = (b - GATHER_BLOCKS - WCONV_BLOCKS) * 256 + tid;
    if (i < M) {
      int id = ids[i];
      bool valid = (id >= 0) && (id < NUM_ITEMS);
      amask[i] = valid ? 1.0f : 0.0f;
      tok[i]   = valid ? (float)id : -1.0f;
    }
  }
}

// ---- async 16B global->LDS (wave-uniform LDS base + lane*16 semantics)
__device__ __forceinline__ void async16(const void* gsrc, void* ldst) {
  __builtin_amdgcn_global_load_lds(
      (const __attribute__((address_space(1))) unsigned int*)gsrc,
      (__attribute__((address_space(3))) unsigned int*)ldst,
      16, 0, 0);
}

// ---- GEMM: C[M,Nd] = A[M,Kd](bf16) @ W[Nd,Kd]^T(bf16), fp32 out
// 128x128 tile, BK=64 (18 K-iters), 4 waves 2x2, wave = 64x64 via 4x4 MFMA 16x16x32.
// LDS XOR chunk swizzle: LDS chunk c of row r holds global chunk (c ^ (r&7)).
// Epilogue: same-wave LDS transpose -> coalesced global_store_dwordx4.
__global__ __launch_bounds__(256) void gemm_kernel(const unsigned short* __restrict__ A,
                                                   const unsigned short* __restrict__ Wb,
                                                   float* __restrict__ C) {
  __shared__ __align__(16) unsigned short lds_a[128 * BK];  // 16 KB
  __shared__ __align__(16) unsigned short lds_b[128 * BK];  // 16 KB

  const int tid  = threadIdx.x;
  const int lane = tid & 63;
  const int wave = tid >> 6;
  const int wm = wave >> 1, wn = wave & 1;
  const int quad = lane >> 4, lm = lane & 15;
  const int m0 = blockIdx.x * 128;
  const int n0 = blockIdx.y * 128;

  // staging: slot idx = r*256 + tid -> LDS row = idx>>3, chunk = idx&7 (8 elems)
  const int srow   = tid >> 3;   // + r*32
  const int schunk = tid & 7;

  f32x4 acc[4][4];
#pragma unroll
  for (int i = 0; i < 4; ++i)
#pragma unroll
    for (int j = 0; j < 4; ++j) acc[i][j] = (f32x4){0.f, 0.f, 0.f, 0.f};

  for (int kt = 0; kt < Kd / BK; ++kt) {
    const int k0 = kt * BK;
#pragma unroll
    for (int r = 0; r < 4; ++r) {
      const int row = r * 32 + srow;
      const int gch = schunk ^ (row & 7);      // XOR swizzle (global side is per-lane)
      const unsigned short* ga = A + (size_t)(m0 + row) * Kd + k0 + gch * 8;
      async16(ga, lds_a + (size_t)(r * 256 + wave * 64) * 8);  // wave-uniform base
      const unsigned short* gb = Wb + (size_t)(n0 + row) * Kd + k0 + gch * 8;
      async16(gb, lds_b + (size_t)(r * 256 + wave * 64) * 8);
    }
    __syncthreads();

#pragma unroll
    for (int h = 0; h < 2; ++h) {              // two 32-wide k-slabs per BK=64
      bf16x8 af[4], bfr[4];
#pragma unroll
      for (int mi = 0; mi < 4; ++mi) {
        const int row = wm * 64 + mi * 16 + lm;
        af[mi] = *(const bf16x8*)(lds_a + row * BK + ((h * 4 + quad) ^ (row & 7)) * 8);
      }
#pragma unroll
      for (int ni = 0; ni < 4; ++ni) {
        const int row = wn * 64 + ni * 16 + lm;
        bfr[ni] = *(const bf16x8*)(lds_b + row * BK + ((h * 4 + quad) ^ (row & 7)) * 8);
      }
#pragma unroll
      for (int mi = 0; mi < 4; ++mi)
#pragma unroll
        for (int ni = 0; ni < 4; ++ni)
          acc[mi][ni] = __builtin_amdgcn_mfma_f32_16x16x32_bf16(af[mi], bfr[ni], acc[mi][ni], 0, 0, 0);
    }
    __syncthreads();
  }

  // ---- epilogue: same-wave LDS transpose -> coalesced dwordx4 stores.
  // Wave-private 4 KB region (4 waves x 1024 floats = 16 KB = lds_a exactly).
  // Safe to reuse lds_a: the K-loop's final __syncthreads covers all waves' reads.
  // No barriers needed below: each wave touches only its own region, and
  // same-wave LDS ops execute in program order (lgkmcnt inserted by compiler).
  float* lw = (float*)lds_a + wave * 1024;   // 16 rows x 64 cols f32
  const int r4  = lane >> 4;     // 0..3
  const int c16 = lane & 15;     // 0..15
#pragma unroll
  for (int mi = 0; mi < 4; ++mi) {
    // C/D layout: col = lane&15, row = quad*4 + reg  [measured m89/m91]
#pragma unroll
    for (int ni = 0; ni < 4; ++ni)
#pragma unroll
      for (int i = 0; i < 4; ++i)
        lw[(quad * 4 + i) * 64 + ni * 16 + lm] = acc[mi][ni][i];
#pragma unroll
    for (int j = 0; j < 4; ++j) {
      float4 v = *(const float4*)(lw + (j * 4 + r4) * 64 + c16 * 4);
      const int row = m0 + wm * 64 + mi * 16 + j * 4 + r4;
      const int col = n0 + wn * 64 + c16 * 4;
      *(float4*)(C + (size_t)row * Nd + col) = v;   // 16 lanes -> 256B contiguous per row
    }
  }
}

extern "C" void kernel_launch(void* const* d_in, const int* in_sizes, int n_in,
                              void* d_out, int out_size, void* d_ws, size_t ws_size,
                              hipStream_t stream) {
  const int*   ids  = (const int*)d_in[0];
  // d_in[1] = lengths: unused (padding already encoded as -1 in ids)
  const float* Esem = (const float*)d_in[2];
  const float* vpr  = (const float*)d_in[3];
  const float* pw   = (const float*)d_in[4];

  float* out_emb   = (float*)d_out;                 // [M, Nd]
  float* out_amask = out_emb + (size_t)M * Nd;      // [M]
  float* out_tok   = out_amask + M;                 // [M]

  unsigned short* A  = (unsigned short*)d_ws;        // [M, Kd] bf16
  unsigned short* Wb = A + (size_t)M * Kd;           // [Nd, Kd] bf16

  prep_kernel<<<GATHER_BLOCKS + WCONV_BLOCKS + MASK_BLOCKS, 256, 0, stream>>>(
      ids, Esem, vpr, pw, A, Wb, out_amask, out_tok);
  gemm_kernel<<<dim3(M / 128, Nd / 128), 256, 0, stream>>>(A, Wb, out_emb);
}

// Round 4
// 519.306 us; speedup vs baseline: 1.0534x; 1.0081x over previous
//
#include <hip/hip_runtime.h>
#include <stdint.h>

// Problem constants (from reference)
constexpr int BB = 64, TT = 200;
constexpr int M  = BB * TT;          // 12800 rows
constexpr int DSEM = 768, DPR = 384;
constexpr int Kd = DSEM + DPR;       // 1152
constexpr int Nd = 2048;             // d_model
constexpr int NUM_ITEMS = 100000;
constexpr int BK = 64;               // K-tile

constexpr int GATHER_BLOCKS = (M * Kd / 8) / 256;   // 7200  (8 elems/thread)
constexpr int WCONV_BLOCKS  = (Nd * Kd / 8) / 256;  // 1152
constexpr int MASK_BLOCKS   = (M + 255) / 256;      // 50

typedef short bf16x8 __attribute__((ext_vector_type(8)));  // 8 bf16 (4 VGPRs)
typedef float f32x4  __attribute__((ext_vector_type(4)));

__device__ __forceinline__ unsigned short f2bf(float f) {
  union { float f; uint32_t u; } v; v.f = f;
  uint32_t u = v.u;
  u += 0x7fffu + ((u >> 16) & 1u);   // RNE
  return (unsigned short)(u >> 16);
}

// ---- fused prep: gather+convert A | proj_w->bf16 | amask/tok  (one dispatch)
__global__ void prep_kernel(const int* __restrict__ ids,
                            const float* __restrict__ Esem,
                            const float* __restrict__ vpr,
                            const float* __restrict__ pw,
                            unsigned short* __restrict__ A,
                            unsigned short* __restrict__ Wb,
                            float* __restrict__ amask,
                            float* __restrict__ tok) {
  const int b = blockIdx.x;
  const int tid = threadIdx.x;
  if (b < GATHER_BLOCKS) {
    // gather + concat + bf16-convert + zero invalid rows into A[M][Kd]
    // 8 elems/thread: 144 chunks per row; chunk boundary 96 splits sem|prompt exactly.
    unsigned g = (unsigned)b * 256u + tid;
    unsigned row = g / 144u;
    unsigned col = (g - row * 144u) * 8u;
    int id = ids[row];
    bool valid = (id >= 0) && (id < NUM_ITEMS);
    int safe = valid ? id : 0;
    const float* src = (col < (unsigned)DSEM)
                         ? (Esem + (size_t)safe * DSEM + col)
                         : (vpr  + (size_t)safe * DPR  + (col - DSEM));
    float4 v0 = *(const float4*)src;
    float4 v1 = *(const float4*)(src + 4);
    if (!valid) {
      v0.x = v0.y = v0.z = v0.w = 0.f;
      v1.x = v1.y = v1.z = v1.w = 0.f;
    }
    ushort4 o0, o1;
    o0.x = f2bf(v0.x); o0.y = f2bf(v0.y); o0.z = f2bf(v0.z); o0.w = f2bf(v0.w);
    o1.x = f2bf(v1.x); o1.y = f2bf(v1.y); o1.z = f2bf(v1.z); o1.w = f2bf(v1.w);
    unsigned short* dst = A + (size_t)row * Kd + col;
    *(ushort4*)dst       = o0;
    *(ushort4*)(dst + 4) = o1;
  } else if (b < GATHER_BLOCKS + WCONV_BLOCKS) {
    int g = (b - GATHER_BLOCKS) * 256 + tid;
    int e = g * 8;
    float4 v0 = *(const float4*)(pw + e);
    float4 v1 = *(const float4*)(pw + e + 4);
    ushort4 o0, o1;
    o0.x = f2bf(v0.x); o0.y = f2bf(v0.y); o0.z = f2bf(v0.z); o0.w = f2bf(v0.w);
    o1.x = f2bf(v1.x); o1.y = f2bf(v1.y); o1.z = f2bf(v1.z); o1.w = f2bf(v1.w);
    *(ushort4*)(Wb + e)     = o0;
    *(ushort4*)(Wb + e + 4) = o1;
  } else {
    int i = (b - GATHER_BLOCKS - WCONV_BLOCKS) * 256 + tid;
    if (i < M) {
      int id = ids[i];
      bool valid = (id >= 0) && (id < NUM_ITEMS);
      amask[i] = valid ? 1.0f : 0.0f;
      tok[i]   = valid ? (float)id : -1.0f;
    }
  }
}

// ---- async 16B global->LDS (wave-uniform LDS base + lane*16 semantics)
__device__ __forceinline__ void async16(const void* gsrc, void* ldst) {
  __builtin_amdgcn_global_load_lds(
      (const __attribute__((address_space(1))) unsigned int*)gsrc,
      (__attribute__((address_space(3))) unsigned int*)ldst,
      16, 0, 0);
}

// ---- GEMM: C[M,Nd] = A[M,Kd](bf16) @ W[Nd,Kd]^T(bf16), fp32 out
// 128x128 tile, BK=64 (18 K-iters), 4 waves 2x2, wave = 64x64 via 4x4 MFMA 16x16x32.
// LDS XOR chunk swizzle: LDS chunk c of row r holds global chunk (c ^ (r&7)).
// 1-D grid 1600 with XCD-locality swizzle: XCD k = b&7 owns n-tiles {k, k+8};
// consecutive local indices pair the two n-blocks of one m-strip so the
// A-strip (294 KB) L2-hits on its second read; W working set/XCD = 588 KB (L2).
__global__ __launch_bounds__(256) void gemm_kernel(const unsigned short* __restrict__ A,
                                                   const unsigned short* __restrict__ Wb,
                                                   float* __restrict__ C) {
  __shared__ __align__(16) unsigned short lds_a[128 * BK];  // 16 KB
  __shared__ __align__(16) unsigned short lds_b[128 * BK];  // 16 KB

  const int tid  = threadIdx.x;
  const int lane = tid & 63;
  const int wave = tid >> 6;
  const int wm = wave >> 1, wn = wave & 1;
  const int quad = lane >> 4, lm = lane & 15;

  // XCD-locality swizzle (dispatch round-robin heuristic: xcd = blockIdx % 8)
  const int b  = blockIdx.x;       // 0..1599
  const int k8 = b & 7;
  const int i  = b >> 3;           // 0..199
  const int m0 = (i >> 1) * 128;                // m-strip 0..99
  const int n0 = (k8 + 8 * (i & 1)) * 128;      // n-tile: {k8, k8+8}

  // staging: slot idx = r*256 + tid -> LDS row = idx>>3, chunk = idx&7 (8 elems)
  const int srow   = tid >> 3;   // + r*32
  const int schunk = tid & 7;

  f32x4 acc[4][4];
#pragma unroll
  for (int i2 = 0; i2 < 4; ++i2)
#pragma unroll
    for (int j = 0; j < 4; ++j) acc[i2][j] = (f32x4){0.f, 0.f, 0.f, 0.f};

  for (int kt = 0; kt < Kd / BK; ++kt) {
    const int k0 = kt * BK;
#pragma unroll
    for (int r = 0; r < 4; ++r) {
      const int row = r * 32 + srow;
      const int gch = schunk ^ (row & 7);      // XOR swizzle (global side is per-lane)
      const unsigned short* ga = A + (size_t)(m0 + row) * Kd + k0 + gch * 8;
      async16(ga, lds_a + (size_t)(r * 256 + wave * 64) * 8);  // wave-uniform base
      const unsigned short* gb = Wb + (size_t)(n0 + row) * Kd + k0 + gch * 8;
      async16(gb, lds_b + (size_t)(r * 256 + wave * 64) * 8);
    }
    __syncthreads();

#pragma unroll
    for (int h = 0; h < 2; ++h) {              // two 32-wide k-slabs per BK=64
      bf16x8 af[4], bfr[4];
#pragma unroll
      for (int mi = 0; mi < 4; ++mi) {
        const int row = wm * 64 + mi * 16 + lm;
        af[mi] = *(const bf16x8*)(lds_a + row * BK + ((h * 4 + quad) ^ (row & 7)) * 8);
      }
#pragma unroll
      for (int ni = 0; ni < 4; ++ni) {
        const int row = wn * 64 + ni * 16 + lm;
        bfr[ni] = *(const bf16x8*)(lds_b + row * BK + ((h * 4 + quad) ^ (row & 7)) * 8);
      }
#pragma unroll
      for (int mi = 0; mi < 4; ++mi)
#pragma unroll
        for (int ni = 0; ni < 4; ++ni)
          acc[mi][ni] = __builtin_amdgcn_mfma_f32_16x16x32_bf16(af[mi], bfr[ni], acc[mi][ni], 0, 0, 0);
    }
    __syncthreads();
  }

  // ---- epilogue: same-wave LDS transpose -> coalesced dwordx4 stores.
  // Wave-private 4 KB region; safe after final __syncthreads (same-wave order).
  float* lw = (float*)lds_a + wave * 1024;   // 16 rows x 64 cols f32
  const int r4  = lane >> 4;     // 0..3
  const int c16 = lane & 15;     // 0..15
#pragma unroll
  for (int mi = 0; mi < 4; ++mi) {
    // C/D layout: col = lane&15, row = quad*4 + reg  [measured m89/m91]
#pragma unroll
    for (int ni = 0; ni < 4; ++ni)
#pragma unroll
      for (int ii = 0; ii < 4; ++ii)
        lw[(quad * 4 + ii) * 64 + ni * 16 + lm] = acc[mi][ni][ii];
#pragma unroll
    for (int j = 0; j < 4; ++j) {
      float4 v = *(const float4*)(lw + (j * 4 + r4) * 64 + c16 * 4);
      const int row = m0 + wm * 64 + mi * 16 + j * 4 + r4;
      const int col = n0 + wn * 64 + c16 * 4;
      *(float4*)(C + (size_t)row * Nd + col) = v;   // 16 lanes -> 256B contiguous
    }
  }
}

extern "C" void kernel_launch(void* const* d_in, const int* in_sizes, int n_in,
                              void* d_out, int out_size, void* d_ws, size_t ws_size,
                              hipStream_t stream) {
  const int*   ids  = (const int*)d_in[0];
  // d_in[1] = lengths: unused (padding already encoded as -1 in ids)
  const float* Esem = (const float*)d_in[2];
  const float* vpr  = (const float*)d_in[3];
  const float* pw   = (const float*)d_in[4];

  float* out_emb   = (float*)d_out;                 // [M, Nd]
  float* out_amask = out_emb + (size_t)M * Nd;      // [M]
  float* out_tok   = out_amask + M;                 // [M]

  unsigned short* A  = (unsigned short*)d_ws;        // [M, Kd] bf16
  unsigned short* Wb = A + (size_t)M * Kd;           // [Nd, Kd] bf16

  prep_kernel<<<GATHER_BLOCKS + WCONV_BLOCKS + MASK_BLOCKS, 256, 0, stream>>>(
      ids, Esem, vpr, pw, A, Wb, out_amask, out_tok);
  gemm_kernel<<<(M / 128) * (Nd / 128), 256, 0, stream>>>(A, Wb, out_emb);
}